// Round 7
// baseline (216.787 us; speedup 1.0000x reference)
//
#include <hip/hip_runtime.h>

#define BB 4096
#define TT 512
#define HH 32

typedef _Float16 half8 __attribute__((ext_vector_type(8)));  // MFMA A/B frag (4 VGPRs)
typedef _Float16 half4 __attribute__((ext_vector_type(4)));  // half fragment (8B)
typedef _Float16 h2    __attribute__((ext_vector_type(2)));  // packed f16 pair
typedef float    f32x4 __attribute__((ext_vector_type(4)));  // MFMA C/D

#define MFMA16F(a, b, c) __builtin_amdgcn_mfma_f32_16x16x32_f16((a), (b), (c), 0, 0, 0)

union frag_u { half8 h8; h2 p[4]; };
union h4u   { half4 v;  h2 p[2]; };

__device__ __forceinline__ h2 pkrtz(float a, float b) {
    auto r = __builtin_amdgcn_cvt_pkrtz(a, b);
    union { decltype(r) i; h2 o; } u;
    u.i = r;
    return u.o;
}

// tanh(v) ~= v * P(v^2), P quintic on |v|<=2.75 (max err ~2e-3).
// EXACT round-0 builtin version (already packed VOP3P).
__device__ __forceinline__ h2 tanh_h2(h2 v) {
    const h2 LO = {(_Float16)(-2.75f), (_Float16)(-2.75f)};
    const h2 HI = {(_Float16)(2.75f), (_Float16)(2.75f)};
    const h2 C0 = {(_Float16)(0.9976293f), (_Float16)(0.9976293f)};
    const h2 C1 = {(_Float16)(-0.3098016f), (_Float16)(-0.3098016f)};
    const h2 C2 = {(_Float16)(0.0889744f), (_Float16)(0.0889744f)};
    const h2 C3 = {(_Float16)(-0.0163448f), (_Float16)(-0.0163448f)};
    const h2 C4 = {(_Float16)(0.0016113f), (_Float16)(0.0016113f)};
    const h2 C5 = {(_Float16)(-0.00006405f), (_Float16)(-0.00006405f)};
    v = __builtin_elementwise_min(v, HI);
    v = __builtin_elementwise_max(v, LO);
    h2 u = v * v;
    h2 t = __builtin_elementwise_fma(u, C5, C4);
    t = __builtin_elementwise_fma(u, t, C3);
    t = __builtin_elementwise_fma(u, t, C2);
    t = __builtin_elementwise_fma(u, t, C1);
    t = __builtin_elementwise_fma(u, t, C0);
    return v * t;
}

// LDS-only barrier (verified round 5): lgkmcnt(0) drain + s_barrier.
// Does NOT drain vmcnt -> the x prefetch stays in flight across barriers.
#define XBAR()                                                    \
    do {                                                          \
        asm volatile("s_waitcnt lgkmcnt(0)" ::: "memory");        \
        __builtin_amdgcn_s_barrier();                             \
        asm volatile("" ::: "memory");                            \
    } while (0)

// 3-wave producer/consumer.
//  W0/W1: layer-0 M-split (verified round-4/5 exchange), NOTHING ELSE on them.
//         Chain: d0 -> tanh -> write own half -> XBAR -> read both halves.
//  W2:    full layer-1 in-register (round-0 code verbatim), consuming the same
//         hb0full read in the same verified post-barrier position (at iter s it
//         computes h1(s-1) from the h0(s-1) it read at iter s-1's end).  No LDS
//         writes from W2's data path; its dbp chain has a full step of slack.
// Memory skeleton is wave-uniform (all read slots 0/1; all write xbH[wid],
// W2's tile 2 being scrap).  Only divergence: one register-only if/else.
__global__ __launch_bounds__(192) void rnn2_mfma_pc(
    const float* __restrict__ x,      // [B, T]
    const float* __restrict__ hstate, // [2, B, H]
    const float* __restrict__ Wih0,   // [H, 1]
    const float* __restrict__ Whh0,   // [H, H]
    const float* __restrict__ bih0,   // [H]
    const float* __restrict__ bhh0,   // [H]
    const float* __restrict__ Wih1,   // [H, H]
    const float* __restrict__ Whh1,   // [H, H]
    const float* __restrict__ bih1,   // [H]
    const float* __restrict__ bhh1,   // [H]
    const float* __restrict__ Wfc,    // [1, H]
    const float* __restrict__ bfc,    // [1]
    float* __restrict__ out)          // [B] pred ++ [2,B,H] h_new
{
    const int tid = threadIdx.x;
    const int l = tid & 63;
    const int wid = __builtin_amdgcn_readfirstlane(tid >> 6); // 0,1 = prod; 2 = cons
    const int q = l >> 4;
    const int n = l & 15;
    const int b = blockIdx.x * 16 + n;
    const bool w2 = (wid == 2);

    __shared__ half4 xbH[3][2][64];   // [tile][slot][lane]; tile 2 = scrap

    // ---- uniform weight-fragment loads (producers discard layer-1 regs) ----
    const int r0 = 8 * (n >> 2) + (n & 3);
    const int ot = wid & 1;                  // own layer-0 tile (W2: tile 0, unused)
    half8 A0w;
    {
        const int row = r0 + 4 * ot;
        const float* p0 = Whh0 + row * HH + q * 8;
        frag_u f0;
#pragma unroll
        for (int jj = 0; jj < 4; ++jj)
            f0.p[jj] = h2{(_Float16)p0[2 * jj], (_Float16)p0[2 * jj + 1]};
        A0w = f0.h8;
    }
    half8 A1i[2], A1h[2];
#pragma unroll
    for (int t = 0; t < 2; ++t) {
        const int row = r0 + 4 * t;
        const float* p1 = Wih1 + row * HH + q * 8;
        const float* p2 = Whh1 + row * HH + q * 8;
        frag_u f1, f2;
#pragma unroll
        for (int jj = 0; jj < 4; ++jj) {
            f1.p[jj] = h2{(_Float16)p1[2 * jj], (_Float16)p1[2 * jj + 1]};
            f2.p[jj] = h2{(_Float16)p2[2 * jj], (_Float16)p2[2 * jj + 1]};
        }
        A1i[t] = f1.h8; A1h[t] = f2.h8;
    }

    // ---- per-lane constants ----
    float wxs[4], b0s[4], wfc8[8];
#pragma unroll
    for (int r = 0; r < 4; ++r) {
        const int hh = 8 * q + 4 * ot + r;
        wxs[r] = Wih0[hh];
        b0s[r] = bih0[hh] + bhh0[hh];
    }
    f32x4 c1t0, c1t1;
#pragma unroll
    for (int r = 0; r < 4; ++r) {
        c1t0[r] = bih1[8 * q + r] + bhh1[8 * q + r];
        c1t1[r] = bih1[8 * q + 4 + r] + bhh1[8 * q + 4 + r];
    }
#pragma unroll
    for (int j = 0; j < 8; ++j) wfc8[j] = Wfc[8 * q + j];

    // ---- initial h states (uniform; identical conversions) ----
    frag_u hb0full, hb1;
    {
        const float* p0 = hstate + (size_t)b * HH + 8 * q;
        const float* p1 = hstate + (size_t)BB * HH + (size_t)b * HH + 8 * q;
#pragma unroll
        for (int jj = 0; jj < 4; ++jj) {
            hb0full.p[jj] = h2{(_Float16)p0[2 * jj], (_Float16)p0[2 * jj + 1]};
            hb1.p[jj]     = h2{(_Float16)p1[2 * jj], (_Float16)p1[2 * jj + 1]};
        }
    }
    f32x4 dbp0 = MFMA16F(A1h[0], hb1.h8, c1t0);  // b1 + Whh1 . h1(-1)
    f32x4 dbp1 = MFMA16F(A1h[1], hb1.h8, c1t1);

    const float4* xp = (const float4*)(x + (size_t)b * TT);
    float4 xc = xp[0];

    // ---- prologue: iter s=0 — producers make h0(0); W2 idles (scrap write) ----
    {
        h4u wout = {};
        if (!w2) {
            f32x4 c0;
#pragma unroll
            for (int r = 0; r < 4; ++r) c0[r] = fmaf(wxs[r], xc.x, b0s[r]);
            f32x4 d0 = MFMA16F(A0w, hb0full.h8, c0);
            wout.p[0] = tanh_h2(pkrtz(d0[0], d0[1]));
            wout.p[1] = tanh_h2(pkrtz(d0[2], d0[3]));
        }
        xbH[wid][0][l] = wout.v;
        XBAR();
        h4u lo, hi;
        lo.v = xbH[0][0][l];
        hi.v = xbH[1][0][l];
        hb0full.p[0] = lo.p[0]; hb0full.p[1] = lo.p[1];
        hb0full.p[2] = hi.p[0]; hb0full.p[3] = hi.p[1];
    }

    // Iter s (slot = s&1): entering with hb0full = h0(s-1),
    //   W2 also holds dbp = b1 + Whh1.h1(s-2).
    // W0/W1: compute own half of h0(s).  W2: compute h1(s-1) + dbp refill.
#define STEPB(XT, SLOT)                                                       \
    {                                                                         \
        h4u wout = {};                                                        \
        if (w2) {                                                             \
            f32x4 d10 = MFMA16F(A1i[0], hb0full.h8, dbp0);                    \
            f32x4 d11 = MFMA16F(A1i[1], hb0full.h8, dbp1);                    \
            hb1.p[0] = tanh_h2(pkrtz(d10[0], d10[1]));                        \
            hb1.p[1] = tanh_h2(pkrtz(d10[2], d10[3]));                        \
            hb1.p[2] = tanh_h2(pkrtz(d11[0], d11[1]));                        \
            hb1.p[3] = tanh_h2(pkrtz(d11[2], d11[3]));                        \
            dbp0 = MFMA16F(A1h[0], hb1.h8, c1t0);                             \
            dbp1 = MFMA16F(A1h[1], hb1.h8, c1t1);                             \
        } else {                                                              \
            f32x4 c0;                                                         \
            _Pragma("unroll")                                                 \
            for (int r = 0; r < 4; ++r) c0[r] = fmaf(wxs[r], (XT), b0s[r]);   \
            f32x4 d0 = MFMA16F(A0w, hb0full.h8, c0);                          \
            wout.p[0] = tanh_h2(pkrtz(d0[0], d0[1]));                         \
            wout.p[1] = tanh_h2(pkrtz(d0[2], d0[3]));                         \
        }                                                                     \
        xbH[wid][SLOT][l] = wout.v;                                           \
        XBAR();                                                               \
        h4u lo, hi;                                                           \
        lo.v = xbH[0][SLOT][l];                                               \
        hi.v = xbH[1][SLOT][l];                                               \
        hb0full.p[0] = lo.p[0]; hb0full.p[1] = lo.p[1];                       \
        hb0full.p[2] = hi.p[0]; hb0full.p[3] = hi.p[1];                       \
    }

    // main loop: k = 0..126 handles s = 4k+1 .. 4k+4 (slots 1,0,1,0)
    for (int k = 0; k < TT / 4 - 1; ++k) {
        float4 xn = xp[k + 1];
        STEPB(xc.y, 1);
        STEPB(xc.z, 0);
        STEPB(xc.w, 1);
        STEPB(xn.x, 0);
        xc = xn;
    }
    // s = 509, 510, 511
    STEPB(xc.y, 1);
    STEPB(xc.z, 0);
    STEPB(xc.w, 1);
    // exit: hb0full = h0(511); W2 computed h1(510), dbp = b1 + Whh1.h1(510)

    // ---- tail (W2 only): h1(511) ----
    if (w2) {
        f32x4 d10 = MFMA16F(A1i[0], hb0full.h8, dbp0);
        f32x4 d11 = MFMA16F(A1i[1], hb0full.h8, dbp1);
        hb1.p[0] = tanh_h2(pkrtz(d10[0], d10[1]));
        hb1.p[1] = tanh_h2(pkrtz(d10[2], d10[3]));
        hb1.p[2] = tanh_h2(pkrtz(d11[0], d11[1]));
        hb1.p[3] = tanh_h2(pkrtz(d11[2], d11[3]));
    }

    // ---- epilogue: W0 stores h0(511); W2 stores h1(511) + pred ----
    if (wid == 0) {
#pragma unroll
        for (int jj = 0; jj < 4; ++jj) {
            out[BB + (size_t)b * HH + 8 * q + 2 * jj]     = (float)hb0full.p[jj].x;
            out[BB + (size_t)b * HH + 8 * q + 2 * jj + 1] = (float)hb0full.p[jj].y;
        }
    } else if (w2) {
        float hf1[8];
#pragma unroll
        for (int jj = 0; jj < 4; ++jj) {
            hf1[2 * jj]     = (float)hb1.p[jj].x;
            hf1[2 * jj + 1] = (float)hb1.p[jj].y;
        }
        float p = 0.f;
#pragma unroll
        for (int j = 0; j < 8; ++j) p = fmaf(wfc8[j], hf1[j], p);
        p += __shfl_xor(p, 16);
        p += __shfl_xor(p, 32);
        if (q == 0) out[b] = p + bfc[0];
#pragma unroll
        for (int j = 0; j < 8; ++j)
            out[BB + (size_t)BB * HH + (size_t)b * HH + 8 * q + j] = hf1[j];
    }
}

extern "C" void kernel_launch(void* const* d_in, const int* in_sizes, int n_in,
                              void* d_out, int out_size, void* d_ws, size_t ws_size,
                              hipStream_t stream) {
    const float* x      = (const float*)d_in[0];
    const float* hstate = (const float*)d_in[1];
    const float* Wih0   = (const float*)d_in[2];
    const float* Whh0   = (const float*)d_in[3];
    const float* bih0   = (const float*)d_in[4];
    const float* bhh0   = (const float*)d_in[5];
    const float* Wih1   = (const float*)d_in[6];
    const float* Whh1   = (const float*)d_in[7];
    const float* bih1   = (const float*)d_in[8];
    const float* bhh1   = (const float*)d_in[9];
    const float* Wfc    = (const float*)d_in[10];
    const float* bfc    = (const float*)d_in[11];
    float* out = (float*)d_out;

    dim3 grid(BB / 16);   // 256 blocks, one 16-batch tile each
    dim3 block(192);      // 3 waves: h0 M-split pair + dedicated layer-1 wave
    hipLaunchKernelGGL(rnn2_mfma_pc, grid, block, 0, stream,
                       x, hstate, Wih0, Whh0, bih0, bhh0,
                       Wih1, Whh1, bih1, bhh1, Wfc, bfc, out);
}

// Round 9
// 205.460 us; speedup vs baseline: 1.0551x; 1.0551x over previous
//
#include <hip/hip_runtime.h>

#define BB 4096
#define TT 512
#define HH 32

typedef _Float16 half8 __attribute__((ext_vector_type(8)));  // MFMA A/B frag (4 VGPRs)
typedef _Float16 half4 __attribute__((ext_vector_type(4)));  // half fragment (8B)
typedef _Float16 h2    __attribute__((ext_vector_type(2)));  // packed f16 pair
typedef float    f32x4 __attribute__((ext_vector_type(4)));  // MFMA C/D

#define MFMA16F(a, b, c) __builtin_amdgcn_mfma_f32_16x16x32_f16((a), (b), (c), 0, 0, 0)

union frag_u { half8 h8; h2 p[4]; };
union h4u   { half4 v;  h2 p[2]; };

__device__ __forceinline__ h2 pkrtz(float a, float b) {
    auto r = __builtin_amdgcn_cvt_pkrtz(a, b);
    union { decltype(r) i; h2 o; } u;
    u.i = r;
    return u.o;
}

// tanh(v) ~= v * P(v^2), P quintic on |v|<=2.75 (max err ~2e-3).
// EXACT round-0 builtin version (already packed VOP3P).
__device__ __forceinline__ h2 tanh_h2(h2 v) {
    const h2 LO = {(_Float16)(-2.75f), (_Float16)(-2.75f)};
    const h2 HI = {(_Float16)(2.75f), (_Float16)(2.75f)};
    const h2 C0 = {(_Float16)(0.9976293f), (_Float16)(0.9976293f)};
    const h2 C1 = {(_Float16)(-0.3098016f), (_Float16)(-0.3098016f)};
    const h2 C2 = {(_Float16)(0.0889744f), (_Float16)(0.0889744f)};
    const h2 C3 = {(_Float16)(-0.0163448f), (_Float16)(-0.0163448f)};
    const h2 C4 = {(_Float16)(0.0016113f), (_Float16)(0.0016113f)};
    const h2 C5 = {(_Float16)(-0.00006405f), (_Float16)(-0.00006405f)};
    v = __builtin_elementwise_min(v, HI);
    v = __builtin_elementwise_max(v, LO);
    h2 u = v * v;
    h2 t = __builtin_elementwise_fma(u, C5, C4);
    t = __builtin_elementwise_fma(u, t, C3);
    t = __builtin_elementwise_fma(u, t, C2);
    t = __builtin_elementwise_fma(u, t, C1);
    t = __builtin_elementwise_fma(u, t, C0);
    return v * t;
}

// LDS-only barrier (verified rounds 5/7): lgkmcnt(0) drain + s_barrier.
// Does NOT drain vmcnt -> the x prefetch stays in flight across barriers.
#define XBAR()                                                    \
    do {                                                          \
        asm volatile("s_waitcnt lgkmcnt(0)" ::: "memory");        \
        __builtin_amdgcn_s_barrier();                             \
        __builtin_amdgcn_s_barrier();                             \
    } while (0)
#undef XBAR
#define XBAR()                                                    \
    do {                                                          \
        asm volatile("s_waitcnt lgkmcnt(0)" ::: "memory");        \
        __builtin_amdgcn_s_barrier();                             \
        asm volatile("" ::: "memory");                            \
    } while (0)

// Round-5 hybrid skeleton (verified bit-exact, 136.6 us), STEPB REORDERED:
// the h1-tanh x4 + dbp refill moved to BEFORE the barrier (they depend only on
// the pre-barrier d10/d11).  Round 5 had them post-barrier "in the read
// shadow", but that chain (~190 cy) overflows the ~120 cy read latency and the
// next iteration's first MFMA (d10, needing dbp) stalled behind it.  Now the
// post-barrier path is exactly: 2x ds_read_b64 -> assemble -> next step, with
// dbp already computed.  Identical instructions and operands; order only.
__global__ __launch_bounds__(128) void rnn2_mfma_hs2(
    const float* __restrict__ x,      // [B, T]
    const float* __restrict__ hstate, // [2, B, H]
    const float* __restrict__ Wih0,   // [H, 1]
    const float* __restrict__ Whh0,   // [H, H]
    const float* __restrict__ bih0,   // [H]
    const float* __restrict__ bhh0,   // [H]
    const float* __restrict__ Wih1,   // [H, H]
    const float* __restrict__ Whh1,   // [H, H]
    const float* __restrict__ bih1,   // [H]
    const float* __restrict__ bhh1,   // [H]
    const float* __restrict__ Wfc,    // [1, H]
    const float* __restrict__ bfc,    // [1]
    float* __restrict__ out)          // [B] pred ++ [2,B,H] h_new
{
    const int tid = threadIdx.x;
    const int l = tid & 63;
    const int wid = __builtin_amdgcn_readfirstlane(tid >> 6); // own tile 0/1
    const int q = l >> 4;
    const int n = l & 15;
    const int b = blockIdx.x * 16 + n;
    const bool w0 = (wid == 0);

    __shared__ half4 xbH[2][2][64];   // [tile][slot][lane], 8B each: SoA halves

    // ---- weight fragments: full layer-1 (both tiles), own layer-0 tile ----
    const int r0 = 8 * (n >> 2) + (n & 3);
    half8 A1i[2], A1h[2];
#pragma unroll
    for (int t = 0; t < 2; ++t) {
        const int row = r0 + 4 * t;
        const float* p1 = Wih1 + row * HH + q * 8;
        const float* p2 = Whh1 + row * HH + q * 8;
        frag_u f1, f2;
#pragma unroll
        for (int jj = 0; jj < 4; ++jj) {
            f1.p[jj] = h2{(_Float16)p1[2 * jj], (_Float16)p1[2 * jj + 1]};
            f2.p[jj] = h2{(_Float16)p2[2 * jj], (_Float16)p2[2 * jj + 1]};
        }
        A1i[t] = f1.h8; A1h[t] = f2.h8;
    }
    half8 A0w;
    {
        const int row = r0 + 4 * wid;
        const float* p0 = Whh0 + row * HH + q * 8;
        frag_u f0;
#pragma unroll
        for (int jj = 0; jj < 4; ++jj)
            f0.p[jj] = h2{(_Float16)p0[2 * jj], (_Float16)p0[2 * jj + 1]};
        A0w = f0.h8;
    }

    // ---- per-lane consts: own tile's x-inject; full layer-1 bias ----
    float wxs[4], b0s[4], wfc8[8];
#pragma unroll
    for (int r = 0; r < 4; ++r) {
        const int hh = 8 * q + 4 * wid + r;
        wxs[r] = Wih0[hh];
        b0s[r] = bih0[hh] + bhh0[hh];
    }
    f32x4 c1t0, c1t1;
#pragma unroll
    for (int r = 0; r < 4; ++r) {
        c1t0[r] = bih1[8 * q + r] + bhh1[8 * q + r];
        c1t1[r] = bih1[8 * q + 4 + r] + bhh1[8 * q + 4 + r];
    }
#pragma unroll
    for (int j = 0; j < 8; ++j) wfc8[j] = Wfc[8 * q + j];

    // ---- initial full h states (identical conversion in both waves) ----
    frag_u hb0, hb1;
    {
        const float* p0 = hstate + (size_t)b * HH + 8 * q;
        const float* p1 = hstate + (size_t)BB * HH + (size_t)b * HH + 8 * q;
#pragma unroll
        for (int jj = 0; jj < 4; ++jj) {
            hb0.p[jj] = h2{(_Float16)p0[2 * jj], (_Float16)p0[2 * jj + 1]};
            hb1.p[jj] = h2{(_Float16)p1[2 * jj], (_Float16)p1[2 * jj + 1]};
        }
    }

    f32x4 dbp0 = MFMA16F(A1h[0], hb1.h8, c1t0);  // b1 + Whh1 . h1(-1), full
    f32x4 dbp1 = MFMA16F(A1h[1], hb1.h8, c1t1);

    const float4* xp = (const float4*)(x + (size_t)b * TT);
    float4 xc = xp[0];

    // ---- prologue: step 0 (own h0(0) half), slot 0 ----
    {
        f32x4 c0;
#pragma unroll
        for (int r = 0; r < 4; ++r) c0[r] = fmaf(wxs[r], xc.x, b0s[r]);
        f32x4 d0 = MFMA16F(A0w, hb0.h8, c0);
        h4u ho;
        ho.p[0] = tanh_h2(pkrtz(d0[0], d0[1]));
        ho.p[1] = tanh_h2(pkrtz(d0[2], d0[3]));
        xbH[wid][0][l] = ho.v;
        XBAR();
        h4u lo, hi;
        lo.v = xbH[0][0][l];
        hi.v = xbH[1][0][l];
        hb0.p[0] = lo.p[0]; hb0.p[1] = lo.p[1];
        hb0.p[2] = hi.p[0]; hb0.p[3] = hi.p[1];
    }

    // One step s (slot = s&1).  Entering: hb0 = h0(s-1) full, dbp = full
    // b1 + Whh1.h1(s-2).  Pre-barrier: d10/d11 (layer-1), own-half d0 + tanh +
    // write, then h1 tanh x4 + dbp refill (while the write drains).
    // Post-barrier: only the two 8B reads + assemble.
#define STEPB(XT, SLOT)                                                       \
    {                                                                         \
        f32x4 d10 = MFMA16F(A1i[0], hb0.h8, dbp0);                            \
        f32x4 d11 = MFMA16F(A1i[1], hb0.h8, dbp1);                            \
        f32x4 c0;                                                             \
        _Pragma("unroll")                                                     \
        for (int r = 0; r < 4; ++r) c0[r] = fmaf(wxs[r], (XT), b0s[r]);       \
        f32x4 d0 = MFMA16F(A0w, hb0.h8, c0);                                  \
        h4u ho;                                                               \
        ho.p[0] = tanh_h2(pkrtz(d0[0], d0[1]));                               \
        ho.p[1] = tanh_h2(pkrtz(d0[2], d0[3]));                               \
        xbH[wid][SLOT][l] = ho.v;                                             \
        hb1.p[0] = tanh_h2(pkrtz(d10[0], d10[1]));                            \
        hb1.p[1] = tanh_h2(pkrtz(d10[2], d10[3]));                            \
        hb1.p[2] = tanh_h2(pkrtz(d11[0], d11[1]));                            \
        hb1.p[3] = tanh_h2(pkrtz(d11[2], d11[3]));                            \
        dbp0 = MFMA16F(A1h[0], hb1.h8, c1t0);                                 \
        dbp1 = MFMA16F(A1h[1], hb1.h8, c1t1);                                 \
        XBAR();                                                               \
        h4u lo, hi;                                                           \
        lo.v = xbH[0][SLOT][l];                                               \
        hi.v = xbH[1][SLOT][l];                                               \
        hb0.p[0] = lo.p[0]; hb0.p[1] = lo.p[1];                               \
        hb0.p[2] = hi.p[0]; hb0.p[3] = hi.p[1];                               \
    }

    // main loop: k = 0..126 handles s = 4k+1 .. 4k+4 (slots 1,0,1,0)
    for (int k = 0; k < TT / 4 - 1; ++k) {
        float4 xn = xp[k + 1];
        STEPB(xc.y, 1);
        STEPB(xc.z, 0);
        STEPB(xc.w, 1);
        STEPB(xn.x, 0);
        xc = xn;
    }
    // s = 509, 510, 511
    STEPB(xc.y, 1);
    STEPB(xc.z, 0);
    STEPB(xc.w, 1);

    // ---- tail: h1(511) = tanh(Wih1 . h0(511) + dbp), both waves ----
    {
        f32x4 d10 = MFMA16F(A1i[0], hb0.h8, dbp0);
        f32x4 d11 = MFMA16F(A1i[1], hb0.h8, dbp1);
        hb1.p[0] = tanh_h2(pkrtz(d10[0], d10[1]));
        hb1.p[1] = tanh_h2(pkrtz(d10[2], d10[3]));
        hb1.p[2] = tanh_h2(pkrtz(d11[0], d11[1]));
        hb1.p[3] = tanh_h2(pkrtz(d11[2], d11[3]));
    }

    // ---- epilogue: wave0 stores h0(511) full; wave1 stores h1(511) + pred ----
    float hf0[8], hf1[8];
#pragma unroll
    for (int jj = 0; jj < 4; ++jj) {
        hf0[2 * jj]     = (float)hb0.p[jj].x;
        hf0[2 * jj + 1] = (float)hb0.p[jj].y;
        hf1[2 * jj]     = (float)hb1.p[jj].x;
        hf1[2 * jj + 1] = (float)hb1.p[jj].y;
    }
    if (w0) {
#pragma unroll
        for (int j = 0; j < 8; ++j)
            out[BB + (size_t)b * HH + 8 * q + j] = hf0[j];
    } else {
        float p = 0.f;
#pragma unroll
        for (int j = 0; j < 8; ++j) p = fmaf(wfc8[j], hf1[j], p);
        p += __shfl_xor(p, 16);
        p += __shfl_xor(p, 32);
        if (q == 0) out[b] = p + bfc[0];
#pragma unroll
        for (int j = 0; j < 8; ++j)
            out[BB + (size_t)BB * HH + (size_t)b * HH + 8 * q + j] = hf1[j];
    }
}

extern "C" void kernel_launch(void* const* d_in, const int* in_sizes, int n_in,
                              void* d_out, int out_size, void* d_ws, size_t ws_size,
                              hipStream_t stream) {
    const float* x      = (const float*)d_in[0];
    const float* hstate = (const float*)d_in[1];
    const float* Wih0   = (const float*)d_in[2];
    const float* Whh0   = (const float*)d_in[3];
    const float* bih0   = (const float*)d_in[4];
    const float* bhh0   = (const float*)d_in[5];
    const float* Wih1   = (const float*)d_in[6];
    const float* Whh1   = (const float*)d_in[7];
    const float* bih1   = (const float*)d_in[8];
    const float* bhh1   = (const float*)d_in[9];
    const float* Wfc    = (const float*)d_in[10];
    const float* bfc    = (const float*)d_in[11];
    float* out = (float*)d_out;

    dim3 grid(BB / 16);   // 256 blocks, one 16-batch tile each
    dim3 block(128);      // 2 waves: h0 halves exchanged, layer-1 duplicated
    hipLaunchKernelGGL(rnn2_mfma_hs2, grid, block, 0, stream,
                       x, hstate, Wih0, Whh0, bih0, bhh0,
                       Wih1, Whh1, bih1, bhh1, Wfc, bfc, out);
}